// Round 1
// baseline (72.861 us; speedup 1.0000x reference)
//
#include <hip/hip_runtime.h>
#include <math.h>

// Batched dynamic bicycle model, 10 substeps of h=0.01f (0.1//0.01 == 9 full
// steps + dt_rem step that rounds to the same f32 0.01).
// Memory-bound elementwise: LDS-staged float4 loads/stores for coalescing.

__device__ __forceinline__ float clipf(float x, float lo, float hi) {
    return fminf(fmaxf(x, lo), hi);
}

__global__ __launch_bounds__(256) void bicycle_kernel(
    const float* __restrict__ state_in,   // (B,9)
    const float* __restrict__ action_in,  // (B,2)
    float* __restrict__ out)              // (B,9)
{
    // Python-float-derived constants, cast to f32 (matches jnp's handling)
    constexpr float MAX_STEER = (float)(30.0 * 3.141592653589793 / 180.0); // 0.5235988
    constexpr float V_EFF_MIN = (float)(20.0 / 3.6);                       // 5.5555553
    constexpr float FY_F_MAX  = (float)(0.9 * 1500.0 * 9.81 * (1.6 / 2.8)); // 7567.7143
    constexpr float FY_R_MAX  = (float)(0.9 * 1500.0 * 9.81 * (1.2 / 2.8)); // 5675.7857

    __shared__ float smem[256 * 9];   // 9216 B
    __shared__ float sact[256 * 2];   // 2048 B

    const int tid = threadIdx.x;
    const size_t rowBase = (size_t)blockIdx.x * 256;

    // ---- coalesced float4 global -> LDS ----
    const float4* g4 = (const float4*)(state_in + rowBase * 9); // block base is 9216B-aligned
    float4* l4 = (float4*)smem;
    l4[tid]        = g4[tid];
    l4[tid + 256]  = g4[tid + 256];
    if (tid < 64) l4[tid + 512] = g4[tid + 512];

    const float4* ga4 = (const float4*)(action_in + rowBase * 2);
    float4* la4 = (float4*)sact;
    if (tid < 128) la4[tid] = ga4[tid];
    __syncthreads();

    // ---- per-thread row (stride 9 is coprime with 32 banks: conflict-free) ----
    const int rb = tid * 9;
    float x     = smem[rb + 0];
    float y     = smem[rb + 1];
    float psi   = smem[rb + 2];
    float v     = smem[rb + 3];
    float a     = smem[rb + 4];
    float delta = smem[rb + 5];
    float beta  = smem[rb + 6];
    float r     = smem[rb + 7];
    // smem[rb+8] (delta_ref) is clipped then overwritten by the action -> ignore

    const float act0 = sact[tid * 2 + 0];
    const float act1 = sact[tid * 2 + 1];

    // reset() clamps
    v     = fmaxf(v, 0.0f);
    delta = clipf(delta, -MAX_STEER, MAX_STEER);
    // step(): clamp action
    const float a_ref     = clipf(act0, -6.0f, 3.0f);
    const float delta_ref = clipf(act1, -MAX_STEER, MAX_STEER);

    const float h = 0.01f;
#pragma unroll
    for (int k = 0; k < 10; ++k) {
        float a_dot     = (a_ref - a) * 10.0f;
        float delta_dot = (delta_ref - delta) * 10.0f;
        float v_eff = fmaxf(v, V_EFF_MIN);
        float inv_v = 1.0f / v_eff;                 // one IEEE divide per substep
        float alpha_f = beta + 1.2f * r * inv_v - delta;
        float alpha_r = beta - 1.6f * r * inv_v;
        float F_yf = clipf(-80000.0f * alpha_f, -FY_F_MAX, FY_F_MAX);
        float F_yr = clipf(-80000.0f * alpha_r, -FY_R_MAX, FY_R_MAX);
        float beta_dot = (F_yf + F_yr) * (inv_v * (1.0f / 1500.0f)) - r;
        float r_dot    = (1.2f * F_yf - 1.6f * F_yr) * (1.0f / 2250.0f);
        float psi_eff  = psi + beta;
        float sn, cs;
        __sincosf(psi_eff, &sn, &cs);
        // all updates from OLD state
        x += v * cs * h;
        y += v * sn * h;
        float v_new = fmaxf(v + a * h, 0.0f);
        psi  += r * h;
        a    += a_dot * h;
        delta = clipf(delta + delta_dot * h, -MAX_STEER, MAX_STEER);
        beta += beta_dot * h;
        r    += r_dot * h;
        v = v_new;
    }

    // ---- write row back to LDS, then coalesced float4 store ----
    smem[rb + 0] = x;
    smem[rb + 1] = y;
    smem[rb + 2] = psi;
    smem[rb + 3] = v;
    smem[rb + 4] = a;
    smem[rb + 5] = delta;
    smem[rb + 6] = beta;
    smem[rb + 7] = r;
    smem[rb + 8] = delta_ref;
    __syncthreads();

    float4* o4 = (float4*)(out + rowBase * 9);
    o4[tid]       = l4[tid];
    o4[tid + 256] = l4[tid + 256];
    if (tid < 64) o4[tid + 512] = l4[tid + 512];
}

extern "C" void kernel_launch(void* const* d_in, const int* in_sizes, int n_in,
                              void* d_out, int out_size, void* d_ws, size_t ws_size,
                              hipStream_t stream) {
    const float* state  = (const float*)d_in[0];
    const float* action = (const float*)d_in[1];
    float* out = (float*)d_out;
    const int rows = in_sizes[0] / 9;        // 4194304
    const int grid = rows / 256;             // 16384 blocks, exact
    bicycle_kernel<<<grid, 256, 0, stream>>>(state, action, out);
}

// Round 2
// 67.503 us; speedup vs baseline: 1.0794x; 1.0794x over previous
//
#include <hip/hip_runtime.h>
#include <math.h>

// Batched dynamic bicycle model, 10 substeps of h=0.01f.
// VALU-bound per round-1 rocprof (VALUBusy 60%, hbm 33%): cut VALU via
// v_rcp_f32 instead of IEEE divide, v_med3 clamps, and 2 rows/thread for ILP.

__device__ __forceinline__ float med3(float x, float lo, float hi) {
    return __builtin_amdgcn_fmed3f(x, lo, hi);
}

__global__ __launch_bounds__(256) void bicycle_kernel(
    const float* __restrict__ state_in,   // (B,9)
    const float* __restrict__ action_in,  // (B,2)
    float* __restrict__ out)              // (B,9)
{
    constexpr float MAX_STEER = (float)(30.0 * 3.141592653589793 / 180.0); // 0.5235988
    constexpr float V_EFF_MIN = (float)(20.0 / 3.6);                       // 5.5555553
    constexpr float FY_F_MAX  = (float)(0.9 * 1500.0 * 9.81 * (1.6 / 2.8)); // 7567.7143
    constexpr float FY_R_MAX  = (float)(0.9 * 1500.0 * 9.81 * (1.2 / 2.8)); // 5675.7857

    constexpr int RPB = 512;                  // rows per block (2 per thread)
    __shared__ float smem[RPB * 9];           // 18432 B

    const int tid = threadIdx.x;
    const size_t rowBase = (size_t)blockIdx.x * RPB;

    // ---- coalesced float4 global -> LDS (1152 float4 per block) ----
    const float4* g4 = (const float4*)(state_in + rowBase * 9);
    float4* l4 = (float4*)smem;
    l4[tid]        = g4[tid];
    l4[tid + 256]  = g4[tid + 256];
    l4[tid + 512]  = g4[tid + 512];
    l4[tid + 768]  = g4[tid + 768];
    if (tid < 128) l4[tid + 1024] = g4[tid + 1024];

    // ---- action: directly coalesced float2 per row ----
    const float2* a2 = (const float2*)action_in + rowBase;
    float2 act[2];
    act[0] = a2[tid];
    act[1] = a2[tid + 256];
    __syncthreads();

    float x[2], y[2], psi[2], v[2], a[2], delta[2], beta[2], r[2];
    float a_ref[2], d_ref[2];

#pragma unroll
    for (int j = 0; j < 2; ++j) {
        const int rb = (tid + j * 256) * 9;   // stride 9: >=2-way LDS aliasing only (free)
        x[j]     = smem[rb + 0];
        y[j]     = smem[rb + 1];
        psi[j]   = smem[rb + 2];
        v[j]     = fmaxf(smem[rb + 3], 0.0f);
        a[j]     = smem[rb + 4];
        delta[j] = med3(smem[rb + 5], -MAX_STEER, MAX_STEER);
        beta[j]  = smem[rb + 6];
        r[j]     = smem[rb + 7];
        a_ref[j] = med3(act[j].x, -6.0f, 3.0f);
        d_ref[j] = med3(act[j].y, -MAX_STEER, MAX_STEER);
    }

#pragma unroll
    for (int k = 0; k < 10; ++k) {
#pragma unroll
        for (int j = 0; j < 2; ++j) {
            float v_eff = fmaxf(v[j], V_EFF_MIN);
            float inv_v = __builtin_amdgcn_rcpf(v_eff);   // ~1 ulp, plenty for 0.104 abs tol
            float t     = r[j] * inv_v;
            float alpha_f = fmaf(1.2f, t, beta[j]) - delta[j];
            float alpha_r = fmaf(-1.6f, t, beta[j]);
            float F_yf = med3(-80000.0f * alpha_f, -FY_F_MAX, FY_F_MAX);
            float F_yr = med3(-80000.0f * alpha_r, -FY_R_MAX, FY_R_MAX);
            float beta_dot = fmaf(F_yf + F_yr, inv_v * (1.0f / 1500.0f), -r[j]);
            float r_dot    = fmaf(1.2f, F_yf, -1.6f * F_yr) * (1.0f / 2250.0f);
            float sn, cs;
            __sincosf(psi[j] + beta[j], &sn, &cs);
            float vh = v[j] * 0.01f;
            x[j] = fmaf(vh, cs, x[j]);
            y[j] = fmaf(vh, sn, y[j]);
            float v_new = fmaxf(fmaf(a[j], 0.01f, v[j]), 0.0f);
            psi[j]   = fmaf(r[j], 0.01f, psi[j]);
            a[j]     = fmaf(a_ref[j] - a[j], 0.1f, a[j]);
            delta[j] = med3(fmaf(d_ref[j] - delta[j], 0.1f, delta[j]), -MAX_STEER, MAX_STEER);
            beta[j]  = fmaf(beta_dot, 0.01f, beta[j]);
            r[j]     = fmaf(r_dot, 0.01f, r[j]);
            v[j]     = v_new;
        }
    }

    // ---- write rows back to LDS, then coalesced float4 store ----
#pragma unroll
    for (int j = 0; j < 2; ++j) {
        const int rb = (tid + j * 256) * 9;
        smem[rb + 0] = x[j];
        smem[rb + 1] = y[j];
        smem[rb + 2] = psi[j];
        smem[rb + 3] = v[j];
        smem[rb + 4] = a[j];
        smem[rb + 5] = delta[j];
        smem[rb + 6] = beta[j];
        smem[rb + 7] = r[j];
        smem[rb + 8] = d_ref[j];
    }
    __syncthreads();

    float4* o4 = (float4*)(out + rowBase * 9);
    o4[tid]       = l4[tid];
    o4[tid + 256] = l4[tid + 256];
    o4[tid + 512] = l4[tid + 512];
    o4[tid + 768] = l4[tid + 768];
    if (tid < 128) o4[tid + 1024] = l4[tid + 1024];
}

extern "C" void kernel_launch(void* const* d_in, const int* in_sizes, int n_in,
                              void* d_out, int out_size, void* d_ws, size_t ws_size,
                              hipStream_t stream) {
    const float* state  = (const float*)d_in[0];
    const float* action = (const float*)d_in[1];
    float* out = (float*)d_out;
    const int rows = in_sizes[0] / 9;        // 4194304
    const int grid = rows / 512;             // 8192 blocks, exact
    bicycle_kernel<<<grid, 256, 0, stream>>>(state, action, out);
}